// Round 10
// baseline (202.812 us; speedup 1.0000x reference)
//
#include <hip/hip_runtime.h>
#include <hip/hip_bf16.h>
#include <math.h>

// GQA forward, round 15: 64x64 GEMM tiles for 2x TLP.
//  - r14 verdict: 2-phase helped (+5us) but GEMMs still ~200 TF, 10x above
//    MFMA floor, grid-capped at 3/2 blocks/CU => latency-bound, TLP-starved.
//    Retile 128x64 -> 64x64: qkv 768->1536 blocks (6/CU, 24 waves/CU),
//    proj 512->1024 (4/CU). Stage = 2 gload_lds; LDS 16KB; 2-phase kept.
//  - V-transpose epilogue simplifies: 64x64 tile = exactly one Vf chunk.
//  - flash (r0 verbatim, FROZEN), prep, Q/K epilogue logic unchanged.

#define N_SEQ 2048
#define EMB   1024
#define NH    16
#define NKV   4
#define HD    64
#define BATCH 2
#define M_TOT 4096
#define QKV_N 1536

typedef __attribute__((ext_vector_type(8)))  short short8;   // 8 bf16
typedef __attribute__((ext_vector_type(4)))  float f32x4;
typedef __attribute__((ext_vector_type(16))) float f32x16;

__device__ __forceinline__ ushort f2bf(float f) {
    union { __hip_bfloat16 h; ushort u; } cv;
    cv.h = __float2bfloat16(f);
    return cv.u;
}
__device__ __forceinline__ float bf2f(ushort u) {
    union { __hip_bfloat16 h; ushort u; } cv;
    cv.u = u;
    return __bfloat162float(cv.h);
}
__device__ __forceinline__ uint pack2bf(float a, float b) {
    union { __hip_bfloat162 h; uint u; } cv;
    cv.h = __float22bfloat162_rn(float2{a, b});   // a -> low 16, b -> high 16
    return cv.u;
}

// async global->LDS, 16B per lane. LDS base must be wave-uniform; HW writes
// base + lane*16; global address is per-lane.
__device__ __forceinline__ void g2lds16(const ushort* g, ushort* l) {
    __builtin_amdgcn_global_load_lds(
        (const __attribute__((address_space(1))) unsigned int*)g,
        (__attribute__((address_space(3))) unsigned int*)l, 16, 0, 0);
}

// stage one 32-wide K-slice (A 64 rows + W 64 rows) into a buffer
__device__ __forceinline__ void stage2(const ushort* Ap, const ushort* Wp,
                                       ushort* AsW, ushort* BsW, int kk)
{
    g2lds16(Ap + kk, AsW);
    g2lds16(Wp + kk, BsW);
}

// one 32-wide K-slice of MFMA from a buffer (64x64 tile, wave owns 16 rows)
__device__ __forceinline__ void mfma_phase(const ushort* __restrict__ Asb,
                                           const ushort* __restrict__ Bsb,
                                           int wm, int l16, int quad,
                                           f32x4 (&acc)[4])
{
    const short8 aF = *(const short8*)&Asb[(wm + l16) * 32 + quad * 8];
    short8 bF[4];
#pragma unroll
    for (int j = 0; j < 4; ++j)
        bF[j] = *(const short8*)&Bsb[(j * 16 + l16) * 32 + quad * 8];
    __builtin_amdgcn_s_setprio(1);
#pragma unroll
    for (int j = 0; j < 4; ++j)
        acc[j] = __builtin_amdgcn_mfma_f32_16x16x32_bf16(aF, bF[j], acc[j], 0, 0, 0);
    __builtin_amdgcn_s_setprio(0);
}

// ---------------------------------------------------------------------------
// Fused prep (unchanged)
// ---------------------------------------------------------------------------
__device__ __forceinline__ void cvt4(const float* __restrict__ s,
                                     ushort* __restrict__ d, long g, long gd) {
    const float4 v = ((const float4*)s)[g];
    ushort4 o;
    o.x = f2bf(v.x); o.y = f2bf(v.y); o.z = f2bf(v.z); o.w = f2bf(v.w);
    ((ushort4*)d)[gd] = o;
}

__global__ __launch_bounds__(256) void prep_kernel(
    const float* __restrict__ x,  const float* __restrict__ wq,
    const float* __restrict__ wk, const float* __restrict__ wv,
    const float* __restrict__ wp, const float* __restrict__ bq,
    const float* __restrict__ bk, const float* __restrict__ bv,
    ushort* __restrict__ xb, ushort* __restrict__ Wqkv,
    ushort* __restrict__ Wproj, float* __restrict__ bqkv)
{
    const long i = (long)blockIdx.x * 256 + threadIdx.x;
    if (i < 1048576) {
        cvt4(x, xb, i, i);
    } else if (i < 1310720) {
        const long g = i - 1048576;
        cvt4(wq, Wqkv, g, g);
    } else if (i < 1376256) {
        const long g = i - 1310720;
        cvt4(wk, Wqkv, g, 262144 + g);
    } else if (i < 1441792) {
        const long g = i - 1376256;
        cvt4(wv, Wqkv, g, 327680 + g);
    } else if (i < 1703936) {
        const long g = i - 1441792;
        cvt4(wp, Wproj, g, g);
    } else if (i < 1704320) {
        const long j = i - 1703936;
        float4 v;
        if (j < 256)      v = ((const float4*)bq)[j];
        else if (j < 320) v = ((const float4*)bk)[j - 256];
        else              v = ((const float4*)bv)[j - 320];
        ((float4*)bqkv)[j] = v;
    }
}

// ---------------------------------------------------------------------------
// QKV GEMM + fused epilogues. 64x64 tile, 4 waves (16 rows each), 2-phase.
// n0 <  1024 : Q head (n0>>6)      -> Qb row-major, scale 0.125 (RMSNorm+RoPE)
// n0 in [1024,1280): K kv-head     -> Kf fragment order (RMSNorm+RoPE)
// n0 >= 1280 : V kv-head           -> Vf fragment order (LDS transpose)
// ---------------------------------------------------------------------------
__global__ __launch_bounds__(256) void gemm_qkv_fused(
    const ushort* __restrict__ A, const ushort* __restrict__ W,
    const float* __restrict__ bias,
    const float* __restrict__ qn_w, const float* __restrict__ kn_w,
    const float* __restrict__ sinp, const float* __restrict__ cosp,
    ushort* __restrict__ Qb, ushort* __restrict__ Kf,
    ushort* __restrict__ Vf)
{
    __shared__ ushort SMEM[8192];          // 2 x (As[64*32] + Bs[64*32]) = 16KB
    ushort* As0 = SMEM;
    ushort* Bs0 = SMEM + 2048;
    ushort* As1 = SMEM + 4096;
    ushort* Bs1 = SMEM + 6144;

    const int tid = threadIdx.x;
    const int m0 = blockIdx.y * 64, n0 = blockIdx.x * 64;
    const int w = tid >> 6, lane = tid & 63;
    const int quad = lane >> 4, l16 = lane & 15;
    const int wm = w * 16;
    const int K = EMB;

    f32x4 acc[4] = {};

    float bb[4];
#pragma unroll
    for (int j = 0; j < 4; ++j) bb[j] = bias[n0 + j * 16 + l16];

    const int r0 = tid >> 2;       // 0..63
    const int c8 = (tid & 3) * 8;
    const ushort* Ap = A + (size_t)(m0 + r0) * K + c8;
    const ushort* Wp = W + (size_t)(n0 + r0) * K + c8;
    ushort* As0W = As0 + w * 512;
    ushort* Bs0W = Bs0 + w * 512;
    ushort* As1W = As1 + w * 512;
    ushort* Bs1W = Bs1 + w * 512;

    stage2(Ap, Wp, As0W, Bs0W, 0);
    for (int k0 = 0; k0 < K; k0 += 64) {
        __syncthreads();                   // buf0 valid; buf1 free
        stage2(Ap, Wp, As1W, Bs1W, k0 + 32);
        mfma_phase(As0, Bs0, wm, l16, quad, acc);
        __syncthreads();                   // buf1 valid; buf0 free
        if (k0 + 64 < K) stage2(Ap, Wp, As0W, Bs0W, k0 + 64);
        mfma_phase(As1, Bs1, wm, l16, quad, acc);
    }

    if (n0 < 1280) {
        // ---- fused RMSNorm + RoPE epilogue (Q or K head tile) ----
        const bool isQ = (n0 < 1024);
        const float* nw = isQ ? qn_w : kn_w;
        const float oscale = isQ ? 0.125f : 1.0f;
        float nwv[4];
#pragma unroll
        for (int j = 0; j < 4; ++j) nwv[j] = nw[j * 16 + l16];

#pragma unroll
        for (int r = 0; r < 4; ++r) {
            const int m = m0 + wm + quad * 4 + r;
            const int n = m & (N_SEQ - 1);
            const int bI = m >> 11;

            float v4[4];
            float ssum = 0.0f;
#pragma unroll
            for (int j = 0; j < 4; ++j) {
                v4[j] = acc[j][r] + bb[j];
                ssum += v4[j] * v4[j];
            }
            // quad-level reduce (16 lanes share this row)
            ssum += __shfl_xor(ssum, 1, 64);
            ssum += __shfl_xor(ssum, 2, 64);
            ssum += __shfl_xor(ssum, 4, 64);
            ssum += __shfl_xor(ssum, 8, 64);
            const float rinv = rsqrtf(ssum * (1.0f / 64.0f) + 1e-6f);

            float tn[4], val[4];
#pragma unroll
            for (int j = 0; j < 4; ++j) tn[j] = v4[j] * rinv * nwv[j];
#pragma unroll
            for (int j = 0; j < 4; ++j) {
                const int d = j * 16 + l16;
                const float rot = (j < 2) ? -tn[j + 2] : tn[j - 2];
                val[j] = (tn[j] * cosp[n * HD + d] + rot * sinp[n * HD + d]) * oscale;
            }

            if (isQ) {
                const size_t qrow =
                    ((size_t)((bI << 4) + (n0 >> 6)) * N_SEQ + n) * HD;
#pragma unroll
                for (int j = 0; j < 4; ++j)
                    Qb[qrow + j * 16 + l16] = f2bf(val[j]);
            } else {
                const int kvh = (n0 >> 6) - 16;
                const int kt = n >> 6, rr = n & 63;
                const int ss2 = rr >> 5, l32k = rr & 31;
                const size_t kb =
                    ((size_t)(bI * NKV + kvh) * 32 + kt) * 4096 + l32k * 16 + l16;
#pragma unroll
                for (int j = 0; j < 4; ++j)
                    Kf[kb + (ss2 * 4 + j) * 512] = f2bf(val[j]);
            }
        }
    } else {
        // ---- V tile: in-block LDS transpose -> fragment-order Vf ----
        // 64x64 tile = exactly one Vf chunk (bkv, kt0).
        const int kvv = (n0 - 1280) >> 6;
        const int bI = m0 >> 11;
        const int kt0 = (m0 & (N_SEQ - 1)) >> 6;
        ushort* L = SMEM;                  // [64][68] = 4352 shorts <= 8192

        const int c = tid >> 5;            // (s*2+t)*2+d2
        const int l32v = tid & 31;
        const int row0 = (c >> 2) * 32 + ((c >> 1) & 1) * 16;  // s*32+t*16
        const int dcol = (c & 1) * 32 + l32v;                  // d2*32+l32v

        __syncthreads();                   // all K-loop LDS reads done
#pragma unroll
        for (int r = 0; r < 4; ++r) {
            const int kl = wm + quad * 4 + r;
#pragma unroll
            for (int j = 0; j < 4; ++j)
                L[kl * 68 + j * 16 + l16] = f2bf(acc[j][r] + bb[j]);
        }
        __syncthreads();
        short8 o0, o1;
#pragma unroll
        for (int e = 0; e < 8; ++e) o0[e] = (short)L[(row0 + e) * 68 + dcol];
#pragma unroll
        for (int e = 0; e < 8; ++e) o1[e] = (short)L[(row0 + 8 + e) * 68 + dcol];
        const size_t vb = ((size_t)(bI * NKV + kvv) * 32 + kt0) * 4096
                          + c * 512 + l32v * 16;
        *(short8*)&Vf[vb] = o0;
        *(short8*)&Vf[vb + 8] = o1;
    }
}

// ---------------------------------------------------------------------------
// bf16 MFMA GEMM, 64x64 tile (proj), 2-phase dbuf pipeline.
// C[m][n] = sum_k A[m][k] W[n][k] + b[n]
// ---------------------------------------------------------------------------
template <bool BF16OUT>
__global__ __launch_bounds__(256) void gemm_mfma_kernel(
    const ushort* __restrict__ A, const ushort* __restrict__ W,
    const float* __restrict__ bias, void* __restrict__ Cout,
    int K, int ldc)
{
    __shared__ ushort SMEM[8192];
    ushort* As0 = SMEM;
    ushort* Bs0 = SMEM + 2048;
    ushort* As1 = SMEM + 4096;
    ushort* Bs1 = SMEM + 6144;

    const int tid = threadIdx.x;
    const int m0 = blockIdx.y * 64, n0 = blockIdx.x * 64;
    const int w = tid >> 6, lane = tid & 63;
    const int quad = lane >> 4, l16 = lane & 15;
    const int wm = w * 16;

    f32x4 acc[4] = {};

    float bb[4];
#pragma unroll
    for (int j = 0; j < 4; ++j) bb[j] = bias[n0 + j * 16 + l16];

    const int r0 = tid >> 2;       // 0..63
    const int c8 = (tid & 3) * 8;
    const ushort* Ap = A + (size_t)(m0 + r0) * K + c8;
    const ushort* Wp = W + (size_t)(n0 + r0) * K + c8;
    ushort* As0W = As0 + w * 512;
    ushort* Bs0W = Bs0 + w * 512;
    ushort* As1W = As1 + w * 512;
    ushort* Bs1W = Bs1 + w * 512;

    stage2(Ap, Wp, As0W, Bs0W, 0);
    for (int k0 = 0; k0 < K; k0 += 64) {
        __syncthreads();                   // buf0 valid; buf1 free
        stage2(Ap, Wp, As1W, Bs1W, k0 + 32);
        mfma_phase(As0, Bs0, wm, l16, quad, acc);
        __syncthreads();                   // buf1 valid; buf0 free
        if (k0 + 64 < K) stage2(Ap, Wp, As0W, Bs0W, k0 + 64);
        mfma_phase(As1, Bs1, wm, l16, quad, acc);
    }

    const int rowb = m0 + wm + quad * 4;
#pragma unroll
    for (int j = 0; j < 4; ++j) {
        const int col = n0 + j * 16 + l16;
#pragma unroll
        for (int r = 0; r < 4; ++r) {
            const float vv = acc[j][r] + bb[j];
            if (BF16OUT)
                ((ushort*)Cout)[(size_t)(rowb + r) * ldc + col] = f2bf(vv);
            else
                ((float*)Cout)[(size_t)(rowb + r) * ldc + col] = vv;
        }
    }
}

// ---------------------------------------------------------------------------
// Barrier-free S^T-layout MFMA flash attention with in-block k-split.
// Round-0 kernel verbatim (FROZEN).
// ---------------------------------------------------------------------------
__global__ __launch_bounds__(256, 4) void flash_mfma32_kernel(
    const ushort* __restrict__ Qb, const ushort* __restrict__ Kf,
    const ushort* __restrict__ Vf, ushort* __restrict__ Ob)
{
    __shared__ float fsm[4352];            // 2 x (2048 O + 64 m + 64 l) = 17.4KB

    const int qt = blockIdx.x;             // 0..31 (64 q-rows)
    const int bh = blockIdx.y;
    const int b = bh >> 4, h = bh & 15;
    const int kvh = h >> 2;
    const int tid = threadIdx.x;
    const int w = tid >> 6, lane = tid & 63;
    const int l32 = lane & 31, l5 = lane >> 5;
    const int qg = w & 1;                  // q-group within block
    const int kh = w >> 1;                 // k-half

    const ushort* Qg = Qb + ((size_t)bh * N_SEQ + qt * 64 + qg * 32) * HD;
    const size_t kvbase = (size_t)(b * NKV + kvh) * (32 * 4096);
    const ushort* Kp = Kf + kvbase;
    const ushort* Vp = Vf + kvbase;
    const int loff = l32 * 16 + l5 * 8;

    // Q^T B-frags: qF[c][j] = Q[q0+l32][c*16 + l5*8 + j]
    short8 qF[4];
#pragma unroll
    for (int c = 0; c < 4; ++c)
        qF[c] = *(const short8*)&Qg[(size_t)l32 * HD + c * 16 + l5 * 8];

    f32x16 Oa[2] = {};                     // O^T d-tiles (d 0-31, 32-63)
    float mrow = -3.0e38f, lrow = 0.0f;

    for (int i = 0; i < 16; ++i) {
        const int kt = kh * 16 + i;
        const ushort* Kt = Kp + kt * 4096;
        const ushort* Vt = Vp + kt * 4096;

        // direct global->reg fragment loads (coalesced, L2-hit)
        short8 kT[2][4];
#pragma unroll
        for (int s = 0; s < 2; ++s)
#pragma unroll
            for (int c = 0; c < 4; ++c)
                kT[s][c] = *(const short8*)&Kt[(s * 4 + c) * 512 + loff];
        short8 vT[2][2][2];
#pragma unroll
        for (int s = 0; s < 2; ++s)
#pragma unroll
            for (int t = 0; t < 2; ++t)
#pragma unroll
                for (int d2 = 0; d2 < 2; ++d2)
                    vT[s][t][d2] = *(const short8*)&Vt[((s * 2 + t) * 2 + d2) * 512 + loff];

        // S^T (32 keys x 32 q-rows) per key-subtile s
        f32x16 Sv[2] = {};
#pragma unroll
        for (int s = 0; s < 2; ++s)
#pragma unroll
            for (int c = 0; c < 4; ++c)
                Sv[s] = __builtin_amdgcn_mfma_f32_32x32x16_bf16(kT[s][c], qF[c], Sv[s], 0, 0, 0);

        // online softmax (keys in-lane + 1 partner shuffle)
        float mx = -3.0e38f;
#pragma unroll
        for (int s = 0; s < 2; ++s)
#pragma unroll
            for (int r = 0; r < 16; ++r) mx = fmaxf(mx, Sv[s][r]);
        mx = fmaxf(mx, __shfl_xor(mx, 32, 64));
        const float mnew = fmaxf(mrow, mx);
        const float alpha = __expf(mrow - mnew);
        mrow = mnew;
        float rs = 0.0f;
#pragma unroll
        for (int s = 0; s < 2; ++s)
#pragma unroll
            for (int r = 0; r < 16; ++r) {
                Sv[s][r] = __expf(Sv[s][r] - mnew);
                rs += Sv[s][r];
            }
        rs += __shfl_xor(rs, 32, 64);
        lrow = lrow * alpha + rs;
#pragma unroll
        for (int t = 0; t < 2; ++t)
#pragma unroll
            for (int r = 0; r < 16; ++r) Oa[t][r] *= alpha;

        // pack P pairs: P2[s][2g+hh] = keys 8g+4*l5+2hh+{0,1} of subtile s
        uint P2[2][8];
#pragma unroll
        for (int s = 0; s < 2; ++s)
#pragma unroll
            for (int g = 0; g < 4; ++g)
#pragma unroll
                for (int hh = 0; hh < 2; ++hh)
                    P2[s][g * 2 + hh] =
                        pack2bf(Sv[s][4 * g + 2 * hh], Sv[s][4 * g + 2 * hh + 1]);

        // P^T B-frags in-register + PV mfma
#pragma unroll
        for (int s = 0; s < 2; ++s)
#pragma unroll
            for (int t = 0; t < 2; ++t) {
                const uint snd0 = l5 ? P2[s][4 * t + 0] : P2[s][4 * t + 2];
                const uint snd1 = l5 ? P2[s][4 * t + 1] : P2[s][4 * t + 3];
                const uint kp0  = l5 ? P2[s][4 * t + 2] : P2[s][4 * t + 0];
                const uint kp1  = l5 ? P2[s][4 * t + 3] : P2[s][4 * t + 1];
                const uint rcv0 = __shfl_xor(snd0, 32, 64);
                const uint rcv1 = __shfl_xor(snd1, 32, 64);
                union { uint u[4]; short8 s8; } pb;
                pb.u[0] = l5 ? rcv0 : kp0;
                pb.u[1] = l5 ? rcv1 : kp1;
                pb.u[2] = l5 ? kp0 : rcv0;
                pb.u[3] = l5 ? kp1 : rcv1;
#pragma unroll
                for (int d2 = 0; d2 < 2; ++d2)
                    Oa[d2] = __builtin_amdgcn_mfma_f32_32x32x16_bf16(
                        vT[s][t][d2], pb.s8, Oa[d2], 0, 0, 0);
            }
    }

    // ---- merge the two k-halves (wave pairs w, w+2 share q-rows) ----
    float* buf = fsm + qg * 2176;
    if (kh == 1) {
#pragma unroll
        for (int d2 = 0; d2 < 2; ++d2)
#pragma unroll
            for (int r = 0; r < 16; ++r)
                buf[(d2 * 16 + r) * 64 + lane] = Oa[d2][r];
        buf[2048 + lane] = mrow;
        buf[2112 + lane] = lrow;
    }
    __syncthreads();

    if (kh == 0) {
        const float mb = buf[2048 + lane];
        const float lb = buf[2112 + lane];
        const float M = fmaxf(mrow, mb);
        const float ea = __expf(mrow - M), eb = __expf(mb - M);
        lrow = lrow * ea + lb * eb;
#pragma unroll
        for (int d2 = 0; d2 < 2; ++d2)
#pragma unroll
            for (int r = 0; r < 16; ++r)
                Oa[d2][r] = Oa[d2][r] * ea + buf[(d2 * 16 + r) * 64 + lane] * eb;
    }
    __syncthreads();                        // merge reads done before Os reuse

    // ---- epilogue: normalize + transpose to row-major via LDS ----
    ushort* Os = (ushort*)fsm;              // [64][68]
    if (kh == 0) {
        const float inv = 1.0f / lrow;
#pragma unroll
        for (int d2 = 0; d2 < 2; ++d2)
#pragma unroll
            for (int r = 0; r < 16; ++r) {
                const int d = d2 * 32 + (r & 3) + 8 * (r >> 2) + 4 * l5;
                Os[(qg * 32 + l32) * 68 + d] = f2bf(Oa[d2][r] * inv);
            }
    }
    __syncthreads();

    const int row = tid >> 2, cc = (tid & 3) * 16;
#pragma unroll
    for (int i = 0; i < 2; ++i) {
        const short8 v = *(const short8*)&Os[row * 68 + cc + i * 8];
        *(short8*)&Ob[((size_t)b * N_SEQ + qt * 64 + row) * EMB + h * HD + cc + i * 8] = v;
    }
}

// ---------------------------------------------------------------------------
extern "C" void kernel_launch(void* const* d_in, const int* in_sizes, int n_in,
                              void* d_out, int out_size, void* d_ws, size_t ws_size,
                              hipStream_t stream)
{
    const float* x      = (const float*)d_in[0];
    const float* sinp   = (const float*)d_in[1];
    const float* cosp   = (const float*)d_in[2];
    const float* wq_w   = (const float*)d_in[3];
    const float* wq_b   = (const float*)d_in[4];
    const float* wk_w   = (const float*)d_in[5];
    const float* wk_b   = (const float*)d_in[6];
    const float* wv_w   = (const float*)d_in[7];
    const float* wv_b   = (const float*)d_in[8];
    const float* qn_w   = (const float*)d_in[9];
    const float* kn_w   = (const float*)d_in[10];
    const float* proj_w = (const float*)d_in[11];
    const float* proj_b = (const float*)d_in[12];
    float* out = (float*)d_out;

    // workspace layout (ushort elements) — Tq slot retained but unused
    ushort* Tq    = (ushort*)d_ws;            // (unused after r12 fusion)
    ushort* xb    = Tq + 6291456;             // 4096*1024 (reused as Ob)
    ushort* Wqkv  = xb + 4194304;             // 1536*1024
    ushort* Wproj = Wqkv + 1572864;           // 1024*1024
    float*  bqkv  = (float*)(Wproj + 1048576);// 1536
    ushort* Qb    = (ushort*)(bqkv + 1536);   // 2*16*2048*64
    ushort* Kf    = Qb + 4194304;             // frag-order K, 1048576
    ushort* Vf    = Kf + 1048576;             // frag-order V^T, 1048576

    prep_kernel<<<6658, 256, 0, stream>>>(x, wq_w, wk_w, wv_w, proj_w,
                                          wq_b, wk_b, wv_b,
                                          xb, Wqkv, Wproj, bqkv);

    gemm_qkv_fused<<<dim3(QKV_N / 64, M_TOT / 64), 256, 0, stream>>>(
        xb, Wqkv, bqkv, qn_w, kn_w, sinp, cosp, Qb, Kf, Vf);

    flash_mfma32_kernel<<<dim3(32, 32), 256, 0, stream>>>(Qb, Kf, Vf, xb);

    gemm_mfma_kernel<false><<<dim3(EMB / 64, M_TOT / 64), 256, 0, stream>>>(
        xb, Wproj, proj_b, out, EMB, EMB);
}

// Round 11
// 197.073 us; speedup vs baseline: 1.0291x; 1.0291x over previous
//
#include <hip/hip_runtime.h>
#include <hip/hip_bf16.h>
#include <math.h>

// GQA forward, round 16: counted-vmcnt 3-buffer GEMM pipeline (T4).
//  - r15 verdict: TLP retile regressed (traffic+barriers doubled). Residual
//    GEMM cost = full vmcnt(0) drain at every __syncthreads (loads get only
//    ~1 compute phase of flight; L2 ~200cy, HBM ~900cy).
//  - Fix: 128x64 tile (r14 geometry, best measured) + 3 LDS buffers,
//    s_waitcnt vmcnt(6) -> s_barrier -> compute -> s_barrier -> restage.
//    Loads fly 2 compute phases + 4 barriers (~500cy). m201-verified sync
//    pattern (wave waits own loads, barrier publishes all). Explicit 5-slice
//    tail drains vmcnt to 0 before epilogues. Requires (K/32)%3==2 (K=1024).
//  - flash (r0 verbatim, FROZEN), prep, all epilogues unchanged from r14.

#define N_SEQ 2048
#define EMB   1024
#define NH    16
#define NKV   4
#define HD    64
#define BATCH 2
#define M_TOT 4096
#define QKV_N 1536

typedef __attribute__((ext_vector_type(8)))  short short8;   // 8 bf16
typedef __attribute__((ext_vector_type(4)))  float f32x4;
typedef __attribute__((ext_vector_type(16))) float f32x16;

#define VMCNT(n) asm volatile("s_waitcnt vmcnt(" #n ")" ::: "memory")
#define BARM()   asm volatile("s_barrier" ::: "memory")

__device__ __forceinline__ ushort f2bf(float f) {
    union { __hip_bfloat16 h; ushort u; } cv;
    cv.h = __float2bfloat16(f);
    return cv.u;
}
__device__ __forceinline__ float bf2f(ushort u) {
    union { __hip_bfloat16 h; ushort u; } cv;
    cv.u = u;
    return __bfloat162float(cv.h);
}
__device__ __forceinline__ uint pack2bf(float a, float b) {
    union { __hip_bfloat162 h; uint u; } cv;
    cv.h = __float22bfloat162_rn(float2{a, b});   // a -> low 16, b -> high 16
    return cv.u;
}

// async global->LDS, 16B per lane. LDS base must be wave-uniform; HW writes
// base + lane*16; global address is per-lane.
__device__ __forceinline__ void g2lds16(const ushort* g, ushort* l) {
    __builtin_amdgcn_global_load_lds(
        (const __attribute__((address_space(1))) unsigned int*)g,
        (__attribute__((address_space(3))) unsigned int*)l, 16, 0, 0);
}

// stage one 32-wide K-slice (A 128 rows + W 64 rows) into buffer buf
// buf layout: As[128*32] at +0, Bs[64*32] at +4096 (shorts)
__device__ __forceinline__ void stage3(const ushort* Ap, const ushort* Wp,
                                       int K, ushort* buf, int w, int kk)
{
    g2lds16(Ap + kk, buf + w * 512);
    g2lds16(Ap + (size_t)64 * K + kk, buf + 2048 + w * 512);
    g2lds16(Wp + kk, buf + 4096 + w * 512);
}

// one 32-wide K-slice of MFMA from buffer buf (128x64 tile, wave owns 32 rows)
__device__ __forceinline__ void mfma_phase(const ushort* __restrict__ buf,
                                           int wm, int l16, int quad,
                                           f32x4 (&acc)[2][4])
{
    const ushort* Asb = buf;
    const ushort* Bsb = buf + 4096;
    short8 aF[2], bF[4];
#pragma unroll
    for (int i = 0; i < 2; ++i)
        aF[i] = *(const short8*)&Asb[(wm + i * 16 + l16) * 32 + quad * 8];
#pragma unroll
    for (int j = 0; j < 4; ++j)
        bF[j] = *(const short8*)&Bsb[(j * 16 + l16) * 32 + quad * 8];
    __builtin_amdgcn_s_setprio(1);
#pragma unroll
    for (int i = 0; i < 2; ++i)
#pragma unroll
        for (int j = 0; j < 4; ++j)
            acc[i][j] = __builtin_amdgcn_mfma_f32_16x16x32_bf16(
                aF[i], bF[j], acc[i][j], 0, 0, 0);
    __builtin_amdgcn_s_setprio(0);
}

// the 3-buffer counted-vmcnt K-loop (K/32 slices; requires (K/32)%3 == 2)
__device__ __forceinline__ void kloop_pipe3(const ushort* Ap, const ushort* Wp,
                                            int K, ushort* b0, ushort* b1,
                                            ushort* b2, int w, int wm,
                                            int l16, int quad,
                                            f32x4 (&acc)[2][4])
{
    stage3(Ap, Wp, K, b0, w, 0);
    stage3(Ap, Wp, K, b1, w, 32);
    stage3(Ap, Wp, K, b2, w, 64);          // 9 loads in flight
    for (int k0 = 0; k0 + 160 < K; k0 += 96) {
        VMCNT(6); BARM();                  // b0 slice ready
        mfma_phase(b0, wm, l16, quad, acc);
        BARM();                            // b0 reads done (WAR)
        stage3(Ap, Wp, K, b0, w, k0 + 96);
        VMCNT(6); BARM();
        mfma_phase(b1, wm, l16, quad, acc);
        BARM();
        stage3(Ap, Wp, K, b1, w, k0 + 128);
        VMCNT(6); BARM();
        mfma_phase(b2, wm, l16, quad, acc);
        BARM();
        stage3(Ap, Wp, K, b2, w, k0 + 160);
    }
    // tail: 5 slices (K-160 .. K-32), drain counts to 0
    VMCNT(6); BARM();
    mfma_phase(b0, wm, l16, quad, acc);    // k = K-160
    BARM();
    stage3(Ap, Wp, K, b0, w, K - 64);
    VMCNT(6); BARM();
    mfma_phase(b1, wm, l16, quad, acc);    // k = K-128
    BARM();
    stage3(Ap, Wp, K, b1, w, K - 32);
    VMCNT(6); BARM();
    mfma_phase(b2, wm, l16, quad, acc);    // k = K-96
    VMCNT(3); BARM();
    mfma_phase(b0, wm, l16, quad, acc);    // k = K-64
    VMCNT(0); BARM();
    mfma_phase(b1, wm, l16, quad, acc);    // k = K-32 ; no loads pending
}

// ---------------------------------------------------------------------------
// Fused prep (unchanged)
// ---------------------------------------------------------------------------
__device__ __forceinline__ void cvt4(const float* __restrict__ s,
                                     ushort* __restrict__ d, long g, long gd) {
    const float4 v = ((const float4*)s)[g];
    ushort4 o;
    o.x = f2bf(v.x); o.y = f2bf(v.y); o.z = f2bf(v.z); o.w = f2bf(v.w);
    ((ushort4*)d)[gd] = o;
}

__global__ __launch_bounds__(256) void prep_kernel(
    const float* __restrict__ x,  const float* __restrict__ wq,
    const float* __restrict__ wk, const float* __restrict__ wv,
    const float* __restrict__ wp, const float* __restrict__ bq,
    const float* __restrict__ bk, const float* __restrict__ bv,
    ushort* __restrict__ xb, ushort* __restrict__ Wqkv,
    ushort* __restrict__ Wproj, float* __restrict__ bqkv)
{
    const long i = (long)blockIdx.x * 256 + threadIdx.x;
    if (i < 1048576) {
        cvt4(x, xb, i, i);
    } else if (i < 1310720) {
        const long g = i - 1048576;
        cvt4(wq, Wqkv, g, g);
    } else if (i < 1376256) {
        const long g = i - 1310720;
        cvt4(wk, Wqkv, g, 262144 + g);
    } else if (i < 1441792) {
        const long g = i - 1376256;
        cvt4(wv, Wqkv, g, 327680 + g);
    } else if (i < 1703936) {
        const long g = i - 1441792;
        cvt4(wp, Wproj, g, g);
    } else if (i < 1704320) {
        const long j = i - 1703936;
        float4 v;
        if (j < 256)      v = ((const float4*)bq)[j];
        else if (j < 320) v = ((const float4*)bk)[j - 256];
        else              v = ((const float4*)bv)[j - 320];
        ((float4*)bqkv)[j] = v;
    }
}

// ---------------------------------------------------------------------------
// QKV GEMM + fused epilogues. 128x64 tile, 4 waves, 3-buffer pipeline.
// n0 <  1024 : Q head (n0>>6)      -> Qb row-major, scale 0.125 (RMSNorm+RoPE)
// n0 in [1024,1280): K kv-head     -> Kf fragment order (RMSNorm+RoPE)
// n0 >= 1280 : V kv-head           -> Vf fragment order (LDS transpose)
// ---------------------------------------------------------------------------
__global__ __launch_bounds__(256) void gemm_qkv_fused(
    const ushort* __restrict__ A, const ushort* __restrict__ W,
    const float* __restrict__ bias,
    const float* __restrict__ qn_w, const float* __restrict__ kn_w,
    const float* __restrict__ sinp, const float* __restrict__ cosp,
    ushort* __restrict__ Qb, ushort* __restrict__ Kf,
    ushort* __restrict__ Vf)
{
    __shared__ ushort SMEM[18432];         // 3 x (As 4096 + Bs 2048) = 36 KB
    ushort* b0 = SMEM;
    ushort* b1 = SMEM + 6144;
    ushort* b2 = SMEM + 12288;

    const int tid = threadIdx.x;
    const int m0 = blockIdx.y * 128, n0 = blockIdx.x * 64;
    const int w = tid >> 6, lane = tid & 63;
    const int quad = lane >> 4, l16 = lane & 15;
    const int wm = w * 32;
    const int K = EMB;

    f32x4 acc[2][4] = {};

    float bb[4];
#pragma unroll
    for (int j = 0; j < 4; ++j) bb[j] = bias[n0 + j * 16 + l16];

    const int r0 = tid >> 2;       // 0..63
    const int c8 = (tid & 3) * 8;
    const ushort* Ap = A + (size_t)(m0 + r0) * K + c8;
    const ushort* Wp = W + (size_t)(n0 + r0) * K + c8;

    kloop_pipe3(Ap, Wp, K, b0, b1, b2, w, wm, l16, quad, acc);

    if (n0 < 1280) {
        // ---- fused RMSNorm + RoPE epilogue (Q or K head tile) ----
        const bool isQ = (n0 < 1024);
        const float* nw = isQ ? qn_w : kn_w;
        const float oscale = isQ ? 0.125f : 1.0f;
        float nwv[4];
#pragma unroll
        for (int j = 0; j < 4; ++j) nwv[j] = nw[j * 16 + l16];

#pragma unroll
        for (int i = 0; i < 2; ++i) {
#pragma unroll
            for (int r = 0; r < 4; ++r) {
                const int m = m0 + wm + i * 16 + quad * 4 + r;
                const int n = m & (N_SEQ - 1);
                const int bI = m >> 11;

                float v4[4];
                float ssum = 0.0f;
#pragma unroll
                for (int j = 0; j < 4; ++j) {
                    v4[j] = acc[i][j][r] + bb[j];
                    ssum += v4[j] * v4[j];
                }
                // quad-level reduce (16 lanes share this row)
                ssum += __shfl_xor(ssum, 1, 64);
                ssum += __shfl_xor(ssum, 2, 64);
                ssum += __shfl_xor(ssum, 4, 64);
                ssum += __shfl_xor(ssum, 8, 64);
                const float rinv = rsqrtf(ssum * (1.0f / 64.0f) + 1e-6f);

                float tn[4], val[4];
#pragma unroll
                for (int j = 0; j < 4; ++j) tn[j] = v4[j] * rinv * nwv[j];
#pragma unroll
                for (int j = 0; j < 4; ++j) {
                    const int d = j * 16 + l16;
                    const float rot = (j < 2) ? -tn[j + 2] : tn[j - 2];
                    val[j] = (tn[j] * cosp[n * HD + d] + rot * sinp[n * HD + d]) * oscale;
                }

                if (isQ) {
                    const size_t qrow =
                        ((size_t)((bI << 4) + (n0 >> 6)) * N_SEQ + n) * HD;
#pragma unroll
                    for (int j = 0; j < 4; ++j)
                        Qb[qrow + j * 16 + l16] = f2bf(val[j]);
                } else {
                    const int kvh = (n0 >> 6) - 16;
                    const int kt = n >> 6, rr = n & 63;
                    const int ss2 = rr >> 5, l32k = rr & 31;
                    const size_t kb =
                        ((size_t)(bI * NKV + kvh) * 32 + kt) * 4096 + l32k * 16 + l16;
#pragma unroll
                    for (int j = 0; j < 4; ++j)
                        Kf[kb + (ss2 * 4 + j) * 512] = f2bf(val[j]);
                }
            }
        }
    } else {
        // ---- V tile: in-block LDS transpose -> fragment-order Vf ----
        // Tile = 128 keys (two 64-key kt chunks) x 64 d (one kv head).
        const int kvv = (n0 - 1280) >> 6;
        const int bI = m0 >> 11;          // m-tile never straddles a batch
        const int kt0 = (m0 & (N_SEQ - 1)) >> 6;
        ushort* L = SMEM;                  // [64][68] = 4352 shorts <= 18432

        const int c = tid >> 5;            // (s*2+t)*2+d2
        const int l32v = tid & 31;
        const int row0 = (c >> 2) * 32 + ((c >> 1) & 1) * 16;  // s*32+t*16
        const int dcol = (c & 1) * 32 + l32v;                  // d2*32+l32v

#pragma unroll
        for (int h = 0; h < 2; ++h) {
            __syncthreads();               // K-loop / prev-half reads done
            if ((w >> 1) == h) {
                const int kl0 = wm - h * 64;   // 0 or 32 within the half
#pragma unroll
                for (int i = 0; i < 2; ++i)
#pragma unroll
                    for (int r = 0; r < 4; ++r) {
                        const int kl = kl0 + i * 16 + quad * 4 + r;
#pragma unroll
                        for (int j = 0; j < 4; ++j)
                            L[kl * 68 + j * 16 + l16] = f2bf(acc[i][j][r] + bb[j]);
                    }
            }
            __syncthreads();
            short8 o0, o1;
#pragma unroll
            for (int e = 0; e < 8; ++e) o0[e] = (short)L[(row0 + e) * 68 + dcol];
#pragma unroll
            for (int e = 0; e < 8; ++e) o1[e] = (short)L[(row0 + 8 + e) * 68 + dcol];
            const size_t vb = ((size_t)(bI * NKV + kvv) * 32 + kt0 + h) * 4096
                              + c * 512 + l32v * 16;
            *(short8*)&Vf[vb] = o0;
            *(short8*)&Vf[vb + 8] = o1;
        }
    }
}

// ---------------------------------------------------------------------------
// bf16 MFMA GEMM, 128x64 tile (proj), 3-buffer counted-vmcnt pipeline.
// C[m][n] = sum_k A[m][k] W[n][k] + b[n]
// ---------------------------------------------------------------------------
template <bool BF16OUT>
__global__ __launch_bounds__(256) void gemm_mfma_kernel(
    const ushort* __restrict__ A, const ushort* __restrict__ W,
    const float* __restrict__ bias, void* __restrict__ Cout,
    int K, int ldc)
{
    __shared__ ushort SMEM[18432];
    ushort* b0 = SMEM;
    ushort* b1 = SMEM + 6144;
    ushort* b2 = SMEM + 12288;

    const int tid = threadIdx.x;
    const int m0 = blockIdx.y * 128, n0 = blockIdx.x * 64;
    const int w = tid >> 6, lane = tid & 63;
    const int quad = lane >> 4, l16 = lane & 15;
    const int wm = w * 32;

    f32x4 acc[2][4] = {};

    float bb[4];
#pragma unroll
    for (int j = 0; j < 4; ++j) bb[j] = bias[n0 + j * 16 + l16];

    const int r0 = tid >> 2;       // 0..63
    const int c8 = (tid & 3) * 8;
    const ushort* Ap = A + (size_t)(m0 + r0) * K + c8;
    const ushort* Wp = W + (size_t)(n0 + r0) * K + c8;

    kloop_pipe3(Ap, Wp, K, b0, b1, b2, w, wm, l16, quad, acc);

#pragma unroll
    for (int i = 0; i < 2; ++i) {
        const int rowb = m0 + wm + i * 16 + quad * 4;
#pragma unroll
        for (int j = 0; j < 4; ++j) {
            const int col = n0 + j * 16 + l16;
#pragma unroll
            for (int r = 0; r < 4; ++r) {
                const float vv = acc[i][j][r] + bb[j];
                if (BF16OUT)
                    ((ushort*)Cout)[(size_t)(rowb + r) * ldc + col] = f2bf(vv);
                else
                    ((float*)Cout)[(size_t)(rowb + r) * ldc + col] = vv;
            }
        }
    }
}

// ---------------------------------------------------------------------------
// Barrier-free S^T-layout MFMA flash attention with in-block k-split.
// Round-0 kernel verbatim (FROZEN).
// ---------------------------------------------------------------------------
__global__ __launch_bounds__(256, 4) void flash_mfma32_kernel(
    const ushort* __restrict__ Qb, const ushort* __restrict__ Kf,
    const ushort* __restrict__ Vf, ushort* __restrict__ Ob)
{
    __shared__ float fsm[4352];            // 2 x (2048 O + 64 m + 64 l) = 17.4KB

    const int qt = blockIdx.x;             // 0..31 (64 q-rows)
    const int bh = blockIdx.y;
    const int b = bh >> 4, h = bh & 15;
    const int kvh = h >> 2;
    const int tid = threadIdx.x;
    const int w = tid >> 6, lane = tid & 63;
    const int l32 = lane & 31, l5 = lane >> 5;
    const int qg = w & 1;                  // q-group within block
    const int kh = w >> 1;                 // k-half

    const ushort* Qg = Qb + ((size_t)bh * N_SEQ + qt * 64 + qg * 32) * HD;
    const size_t kvbase = (size_t)(b * NKV + kvh) * (32 * 4096);
    const ushort* Kp = Kf + kvbase;
    const ushort* Vp = Vf + kvbase;
    const int loff = l32 * 16 + l5 * 8;

    // Q^T B-frags: qF[c][j] = Q[q0+l32][c*16 + l5*8 + j]
    short8 qF[4];
#pragma unroll
    for (int c = 0; c < 4; ++c)
        qF[c] = *(const short8*)&Qg[(size_t)l32 * HD + c * 16 + l5 * 8];

    f32x16 Oa[2] = {};                     // O^T d-tiles (d 0-31, 32-63)
    float mrow = -3.0e38f, lrow = 0.0f;

    for (int i = 0; i < 16; ++i) {
        const int kt = kh * 16 + i;
        const ushort* Kt = Kp + kt * 4096;
        const ushort* Vt = Vp + kt * 4096;

        // direct global->reg fragment loads (coalesced, L2-hit)
        short8 kT[2][4];
#pragma unroll
        for (int s = 0; s < 2; ++s)
#pragma unroll
            for (int c = 0; c < 4; ++c)
                kT[s][c] = *(const short8*)&Kt[(s * 4 + c) * 512 + loff];
        short8 vT[2][2][2];
#pragma unroll
        for (int s = 0; s < 2; ++s)
#pragma unroll
            for (int t = 0; t < 2; ++t)
#pragma unroll
                for (int d2 = 0; d2 < 2; ++d2)
                    vT[s][t][d2] = *(const short8*)&Vt[((s * 2 + t) * 2 + d2) * 512 + loff];

        // S^T (32 keys x 32 q-rows) per key-subtile s
        f32x16 Sv[2] = {};
#pragma unroll
        for (int s = 0; s < 2; ++s)
#pragma unroll
            for (int c = 0; c < 4; ++c)
                Sv[s] = __builtin_amdgcn_mfma_f32_32x32x16_bf16(kT[s][c], qF[c], Sv[s], 0, 0, 0);

        // online softmax (keys in-lane + 1 partner shuffle)
        float mx = -3.0e38f;
#pragma unroll
        for (int s = 0; s < 2; ++s)
#pragma unroll
            for (int r = 0; r < 16; ++r) mx = fmaxf(mx, Sv[s][r]);
        mx = fmaxf(mx, __shfl_xor(mx, 32, 64));
        const float mnew = fmaxf(mrow, mx);
        const float alpha = __expf(mrow - mnew);
        mrow = mnew;
        float rs = 0.0f;
#pragma unroll
        for (int s = 0; s < 2; ++s)
#pragma unroll
            for (int r = 0; r < 16; ++r) {
                Sv[s][r] = __expf(Sv[s][r] - mnew);
                rs += Sv[s][r];
            }
        rs += __shfl_xor(rs, 32, 64);
        lrow = lrow * alpha + rs;
#pragma unroll
        for (int t = 0; t < 2; ++t)
#pragma unroll
            for (int r = 0; r < 16; ++r) Oa[t][r] *= alpha;

        // pack P pairs: P2[s][2g+hh] = keys 8g+4*l5+2hh+{0,1} of subtile s
        uint P2[2][8];
#pragma unroll
        for (int s = 0; s < 2; ++s)
#pragma unroll
            for (int g = 0; g < 4; ++g)
#pragma unroll
                for (int hh = 0; hh < 2; ++hh)
                    P2[s][g * 2 + hh] =
                        pack2bf(Sv[s][4 * g + 2 * hh], Sv[s][4 * g + 2 * hh + 1]);

        // P^T B-frags in-register + PV mfma
#pragma unroll
        for (int s = 0; s < 2; ++s)
#pragma unroll
            for (int t = 0; t < 2; ++t) {
                const uint snd0 = l5 ? P2[s][4 * t + 0] : P2[s][4 * t + 2];
                const uint snd1 = l5 ? P2[s][4 * t + 1] : P2[s][4 * t + 3];
                const uint kp0  = l5 ? P2[s][4 * t + 2] : P2[s][4 * t + 0];
                const uint kp1  = l5 ? P2[s][4 * t + 3] : P2[s][4 * t + 1];
                const uint rcv0 = __shfl_xor(snd0, 32, 64);
                const uint rcv1 = __shfl_xor(snd1, 32, 64);
                union { uint u[4]; short8 s8; } pb;
                pb.u[0] = l5 ? rcv0 : kp0;
                pb.u[1] = l5 ? rcv1 : kp1;
                pb.u[2] = l5 ? kp0 : rcv0;
                pb.u[3] = l5 ? kp1 : rcv1;
#pragma unroll
                for (int d2 = 0; d2 < 2; ++d2)
                    Oa[d2] = __builtin_amdgcn_mfma_f32_32x32x16_bf16(
                        vT[s][t][d2], pb.s8, Oa[d2], 0, 0, 0);
            }
    }

    // ---- merge the two k-halves (wave pairs w, w+2 share q-rows) ----
    float* buf = fsm + qg * 2176;
    if (kh == 1) {
#pragma unroll
        for (int d2 = 0; d2 < 2; ++d2)
#pragma unroll
            for (int r = 0; r < 16; ++r)
                buf[(d2 * 16 + r) * 64 + lane] = Oa[d2][r];
        buf[2048 + lane] = mrow;
        buf[2112 + lane] = lrow;
    }
    __syncthreads();

    if (kh == 0) {
        const float mb = buf[2048 + lane];
        const float lb = buf[2112 + lane];
        const float M = fmaxf(mrow, mb);
        const float ea = __expf(mrow - M), eb = __expf(mb - M);
        lrow = lrow * ea + lb * eb;
#pragma unroll
        for (int d2 = 0; d2 < 2; ++d2)
#pragma unroll
            for (int r = 0; r < 16; ++r)
                Oa[d2][r] = Oa[d2][r] * ea + buf[(d2 * 16 + r) * 64 + lane] * eb;
    }
    __syncthreads();                        // merge reads done before Os reuse

    // ---- epilogue: normalize + transpose to row-major via LDS ----
    ushort* Os = (ushort*)fsm;              // [64][68]
    if (kh == 0) {
        const float inv = 1.0f / lrow;
#pragma unroll
        for (int d2 = 0; d2 < 2; ++d2)
#pragma unroll
            for (int r = 0; r < 16; ++r) {
                const int d = d2 * 32 + (r & 3) + 8 * (r >> 2) + 4 * l5;
                Os[(qg * 32 + l32) * 68 + d] = f2bf(Oa[d2][r] * inv);
            }
    }
    __syncthreads();

    const int row = tid >> 2, cc = (tid & 3) * 16;
#pragma unroll
    for (int i = 0; i < 2; ++i) {
        const short8 v = *(const short8*)&Os[row * 68 + cc + i * 8];
        *(short8*)&Ob[((size_t)b * N_SEQ + qt * 64 + row) * EMB + h * HD + cc + i * 8] = v;
    }
}

// ---------------------------------------------------------------------------
extern "C" void kernel_launch(void* const* d_in, const int* in_sizes, int n_in,
                              void* d_out, int out_size, void* d_ws, size_t ws_size,
                              hipStream_t stream)
{
    const float* x      = (const float*)d_in[0];
    const float* sinp   = (const float*)d_in[1];
    const float* cosp   = (const float*)d_in[2];
    const float* wq_w   = (const float*)d_in[3];
    const float* wq_b   = (const float*)d_in[4];
    const float* wk_w   = (const float*)d_in[5];
    const float* wk_b   = (const float*)d_in[6];
    const float* wv_w   = (const float*)d_in[7];
    const float* wv_b   = (const float*)d_in[8];
    const float* qn_w   = (const float*)d_in[9];
    const float* kn_w   = (const float*)d_in[10];
    const float* proj_w = (const float*)d_in[11];
    const float* proj_b = (const float*)d_in[12];
    float* out = (float*)d_out;

    // workspace layout (ushort elements) — Tq slot retained but unused
    ushort* Tq    = (ushort*)d_ws;            // (unused after r12 fusion)
    ushort* xb    = Tq + 6291456;             // 4096*1024 (reused as Ob)
    ushort* Wqkv  = xb + 4194304;             // 1536*1024
    ushort* Wproj = Wqkv + 1572864;           // 1024*1024
    float*  bqkv  = (float*)(Wproj + 1048576);// 1536
    ushort* Qb    = (ushort*)(bqkv + 1536);   // 2*16*2048*64
    ushort* Kf    = Qb + 4194304;             // frag-order K, 1048576
    ushort* Vf    = Kf + 1048576;             // frag-order V^T, 1048576

    prep_kernel<<<6658, 256, 0, stream>>>(x, wq_w, wk_w, wv_w, proj_w,
                                          wq_b, wk_b, wv_b,
                                          xb, Wqkv, Wproj, bqkv);

    gemm_qkv_fused<<<dim3(QKV_N / 64, M_TOT / 128), 256, 0, stream>>>(
        xb, Wqkv, bqkv, qn_w, kn_w, sinp, cosp, Qb, Kf, Vf);

    flash_mfma32_kernel<<<dim3(32, 32), 256, 0, stream>>>(Qb, Kf, Vf, xb);

    gemm_mfma_kernel<false><<<dim3(EMB / 64, M_TOT / 128), 256, 0, stream>>>(
        xb, Wproj, proj_b, out, EMB, EMB);
}

// Round 12
// 195.153 us; speedup vs baseline: 1.0392x; 1.0098x over previous
//
#include <hip/hip_runtime.h>
#include <hip/hip_bf16.h>
#include <math.h>

// GQA forward, round 17: XCD-aware block swizzle (T1) on both GEMMs.
//  - r16 verdict: counted-vmcnt +2us only => in-block pipelining exhausted.
//    Traffic audit: x-fastest grid linearization round-robins same-A-strip
//    blocks across XCDs => every XCD L2 pulls ~all of A (8x duplication,
//    ~67MB qkv + ~67MB proj beyond L2). Fix: 1D grid + bijective swizzle
//    swz=(bid%8)*(nwg/8)+bid/8, x-fastest decompose => each XCD owns 4
//    contiguous m-strips; A becomes L2-resident per XCD.
//  - K-loop (3-buffer counted-vmcnt, r16), epilogues, flash (r0, FROZEN),
//    prep: byte-identical.

#define N_SEQ 2048
#define EMB   1024
#define NH    16
#define NKV   4
#define HD    64
#define BATCH 2
#define M_TOT 4096
#define QKV_N 1536

typedef __attribute__((ext_vector_type(8)))  short short8;   // 8 bf16
typedef __attribute__((ext_vector_type(4)))  float f32x4;
typedef __attribute__((ext_vector_type(16))) float f32x16;

#define VMCNT(n) asm volatile("s_waitcnt vmcnt(" #n ")" ::: "memory")
#define BARM()   asm volatile("s_barrier" ::: "memory")

__device__ __forceinline__ ushort f2bf(float f) {
    union { __hip_bfloat16 h; ushort u; } cv;
    cv.h = __float2bfloat16(f);
    return cv.u;
}
__device__ __forceinline__ float bf2f(ushort u) {
    union { __hip_bfloat16 h; ushort u; } cv;
    cv.u = u;
    return __bfloat162float(cv.h);
}
__device__ __forceinline__ uint pack2bf(float a, float b) {
    union { __hip_bfloat162 h; uint u; } cv;
    cv.h = __float22bfloat162_rn(float2{a, b});   // a -> low 16, b -> high 16
    return cv.u;
}

// async global->LDS, 16B per lane. LDS base must be wave-uniform; HW writes
// base + lane*16; global address is per-lane.
__device__ __forceinline__ void g2lds16(const ushort* g, ushort* l) {
    __builtin_amdgcn_global_load_lds(
        (const __attribute__((address_space(1))) unsigned int*)g,
        (__attribute__((address_space(3))) unsigned int*)l, 16, 0, 0);
}

// stage one 32-wide K-slice (A 128 rows + W 64 rows) into buffer buf
// buf layout: As[128*32] at +0, Bs[64*32] at +4096 (shorts)
__device__ __forceinline__ void stage3(const ushort* Ap, const ushort* Wp,
                                       int K, ushort* buf, int w, int kk)
{
    g2lds16(Ap + kk, buf + w * 512);
    g2lds16(Ap + (size_t)64 * K + kk, buf + 2048 + w * 512);
    g2lds16(Wp + kk, buf + 4096 + w * 512);
}

// one 32-wide K-slice of MFMA from buffer buf (128x64 tile, wave owns 32 rows)
__device__ __forceinline__ void mfma_phase(const ushort* __restrict__ buf,
                                           int wm, int l16, int quad,
                                           f32x4 (&acc)[2][4])
{
    const ushort* Asb = buf;
    const ushort* Bsb = buf + 4096;
    short8 aF[2], bF[4];
#pragma unroll
    for (int i = 0; i < 2; ++i)
        aF[i] = *(const short8*)&Asb[(wm + i * 16 + l16) * 32 + quad * 8];
#pragma unroll
    for (int j = 0; j < 4; ++j)
        bF[j] = *(const short8*)&Bsb[(j * 16 + l16) * 32 + quad * 8];
    __builtin_amdgcn_s_setprio(1);
#pragma unroll
    for (int i = 0; i < 2; ++i)
#pragma unroll
        for (int j = 0; j < 4; ++j)
            acc[i][j] = __builtin_amdgcn_mfma_f32_16x16x32_bf16(
                aF[i], bF[j], acc[i][j], 0, 0, 0);
    __builtin_amdgcn_s_setprio(0);
}

// the 3-buffer counted-vmcnt K-loop (K/32 slices; requires (K/32)%3 == 2)
__device__ __forceinline__ void kloop_pipe3(const ushort* Ap, const ushort* Wp,
                                            int K, ushort* b0, ushort* b1,
                                            ushort* b2, int w, int wm,
                                            int l16, int quad,
                                            f32x4 (&acc)[2][4])
{
    stage3(Ap, Wp, K, b0, w, 0);
    stage3(Ap, Wp, K, b1, w, 32);
    stage3(Ap, Wp, K, b2, w, 64);          // 9 loads in flight
    for (int k0 = 0; k0 + 160 < K; k0 += 96) {
        VMCNT(6); BARM();                  // b0 slice ready
        mfma_phase(b0, wm, l16, quad, acc);
        BARM();                            // b0 reads done (WAR)
        stage3(Ap, Wp, K, b0, w, k0 + 96);
        VMCNT(6); BARM();
        mfma_phase(b1, wm, l16, quad, acc);
        BARM();
        stage3(Ap, Wp, K, b1, w, k0 + 128);
        VMCNT(6); BARM();
        mfma_phase(b2, wm, l16, quad, acc);
        BARM();
        stage3(Ap, Wp, K, b2, w, k0 + 160);
    }
    // tail: 5 slices (K-160 .. K-32), drain counts to 0
    VMCNT(6); BARM();
    mfma_phase(b0, wm, l16, quad, acc);    // k = K-160
    BARM();
    stage3(Ap, Wp, K, b0, w, K - 64);
    VMCNT(6); BARM();
    mfma_phase(b1, wm, l16, quad, acc);    // k = K-128
    BARM();
    stage3(Ap, Wp, K, b1, w, K - 32);
    VMCNT(6); BARM();
    mfma_phase(b2, wm, l16, quad, acc);    // k = K-96
    VMCNT(3); BARM();
    mfma_phase(b0, wm, l16, quad, acc);    // k = K-64
    VMCNT(0); BARM();
    mfma_phase(b1, wm, l16, quad, acc);    // k = K-32 ; no loads pending
}

// ---------------------------------------------------------------------------
// Fused prep (unchanged)
// ---------------------------------------------------------------------------
__device__ __forceinline__ void cvt4(const float* __restrict__ s,
                                     ushort* __restrict__ d, long g, long gd) {
    const float4 v = ((const float4*)s)[g];
    ushort4 o;
    o.x = f2bf(v.x); o.y = f2bf(v.y); o.z = f2bf(v.z); o.w = f2bf(v.w);
    ((ushort4*)d)[gd] = o;
}

__global__ __launch_bounds__(256) void prep_kernel(
    const float* __restrict__ x,  const float* __restrict__ wq,
    const float* __restrict__ wk, const float* __restrict__ wv,
    const float* __restrict__ wp, const float* __restrict__ bq,
    const float* __restrict__ bk, const float* __restrict__ bv,
    ushort* __restrict__ xb, ushort* __restrict__ Wqkv,
    ushort* __restrict__ Wproj, float* __restrict__ bqkv)
{
    const long i = (long)blockIdx.x * 256 + threadIdx.x;
    if (i < 1048576) {
        cvt4(x, xb, i, i);
    } else if (i < 1310720) {
        const long g = i - 1048576;
        cvt4(wq, Wqkv, g, g);
    } else if (i < 1376256) {
        const long g = i - 1310720;
        cvt4(wk, Wqkv, g, 262144 + g);
    } else if (i < 1441792) {
        const long g = i - 1376256;
        cvt4(wv, Wqkv, g, 327680 + g);
    } else if (i < 1703936) {
        const long g = i - 1441792;
        cvt4(wp, Wproj, g, g);
    } else if (i < 1704320) {
        const long j = i - 1703936;
        float4 v;
        if (j < 256)      v = ((const float4*)bq)[j];
        else if (j < 320) v = ((const float4*)bk)[j - 256];
        else              v = ((const float4*)bv)[j - 320];
        ((float4*)bqkv)[j] = v;
    }
}

// ---------------------------------------------------------------------------
// QKV GEMM + fused epilogues. 128x64 tile, 4 waves, 3-buffer pipeline.
// 1D grid 768 blocks, XCD-swizzled: XCD k owns m-strips [4k, 4k+4).
// n0 <  1024 : Q head (n0>>6)      -> Qb row-major, scale 0.125 (RMSNorm+RoPE)
// n0 in [1024,1280): K kv-head     -> Kf fragment order (RMSNorm+RoPE)
// n0 >= 1280 : V kv-head           -> Vf fragment order (LDS transpose)
// ---------------------------------------------------------------------------
__global__ __launch_bounds__(256) void gemm_qkv_fused(
    const ushort* __restrict__ A, const ushort* __restrict__ W,
    const float* __restrict__ bias,
    const float* __restrict__ qn_w, const float* __restrict__ kn_w,
    const float* __restrict__ sinp, const float* __restrict__ cosp,
    ushort* __restrict__ Qb, ushort* __restrict__ Kf,
    ushort* __restrict__ Vf)
{
    __shared__ ushort SMEM[18432];         // 3 x (As 4096 + Bs 2048) = 36 KB
    ushort* b0 = SMEM;
    ushort* b1 = SMEM + 6144;
    ushort* b2 = SMEM + 12288;

    const int tid = threadIdx.x;
    // T1 XCD swizzle: nwg=768 (24 x 32), 96 blocks per XCD, x-fastest
    const int bid = blockIdx.x;
    const int swz = (bid & 7) * 96 + (bid >> 3);
    const int bx = swz % 24, by = swz / 24;
    const int m0 = by * 128, n0 = bx * 64;
    const int w = tid >> 6, lane = tid & 63;
    const int quad = lane >> 4, l16 = lane & 15;
    const int wm = w * 32;
    const int K = EMB;

    f32x4 acc[2][4] = {};

    float bb[4];
#pragma unroll
    for (int j = 0; j < 4; ++j) bb[j] = bias[n0 + j * 16 + l16];

    const int r0 = tid >> 2;       // 0..63
    const int c8 = (tid & 3) * 8;
    const ushort* Ap = A + (size_t)(m0 + r0) * K + c8;
    const ushort* Wp = W + (size_t)(n0 + r0) * K + c8;

    kloop_pipe3(Ap, Wp, K, b0, b1, b2, w, wm, l16, quad, acc);

    if (n0 < 1280) {
        // ---- fused RMSNorm + RoPE epilogue (Q or K head tile) ----
        const bool isQ = (n0 < 1024);
        const float* nw = isQ ? qn_w : kn_w;
        const float oscale = isQ ? 0.125f : 1.0f;
        float nwv[4];
#pragma unroll
        for (int j = 0; j < 4; ++j) nwv[j] = nw[j * 16 + l16];

#pragma unroll
        for (int i = 0; i < 2; ++i) {
#pragma unroll
            for (int r = 0; r < 4; ++r) {
                const int m = m0 + wm + i * 16 + quad * 4 + r;
                const int n = m & (N_SEQ - 1);
                const int bI = m >> 11;

                float v4[4];
                float ssum = 0.0f;
#pragma unroll
                for (int j = 0; j < 4; ++j) {
                    v4[j] = acc[i][j][r] + bb[j];
                    ssum += v4[j] * v4[j];
                }
                // quad-level reduce (16 lanes share this row)
                ssum += __shfl_xor(ssum, 1, 64);
                ssum += __shfl_xor(ssum, 2, 64);
                ssum += __shfl_xor(ssum, 4, 64);
                ssum += __shfl_xor(ssum, 8, 64);
                const float rinv = rsqrtf(ssum * (1.0f / 64.0f) + 1e-6f);

                float tn[4], val[4];
#pragma unroll
                for (int j = 0; j < 4; ++j) tn[j] = v4[j] * rinv * nwv[j];
#pragma unroll
                for (int j = 0; j < 4; ++j) {
                    const int d = j * 16 + l16;
                    const float rot = (j < 2) ? -tn[j + 2] : tn[j - 2];
                    val[j] = (tn[j] * cosp[n * HD + d] + rot * sinp[n * HD + d]) * oscale;
                }

                if (isQ) {
                    const size_t qrow =
                        ((size_t)((bI << 4) + (n0 >> 6)) * N_SEQ + n) * HD;
#pragma unroll
                    for (int j = 0; j < 4; ++j)
                        Qb[qrow + j * 16 + l16] = f2bf(val[j]);
                } else {
                    const int kvh = (n0 >> 6) - 16;
                    const int kt = n >> 6, rr = n & 63;
                    const int ss2 = rr >> 5, l32k = rr & 31;
                    const size_t kb =
                        ((size_t)(bI * NKV + kvh) * 32 + kt) * 4096 + l32k * 16 + l16;
#pragma unroll
                    for (int j = 0; j < 4; ++j)
                        Kf[kb + (ss2 * 4 + j) * 512] = f2bf(val[j]);
                }
            }
        }
    } else {
        // ---- V tile: in-block LDS transpose -> fragment-order Vf ----
        // Tile = 128 keys (two 64-key kt chunks) x 64 d (one kv head).
        const int kvv = (n0 - 1280) >> 6;
        const int bI = m0 >> 11;          // m-tile never straddles a batch
        const int kt0 = (m0 & (N_SEQ - 1)) >> 6;
        ushort* L = SMEM;                  // [64][68] = 4352 shorts <= 18432

        const int c = tid >> 5;            // (s*2+t)*2+d2
        const int l32v = tid & 31;
        const int row0 = (c >> 2) * 32 + ((c >> 1) & 1) * 16;  // s*32+t*16
        const int dcol = (c & 1) * 32 + l32v;                  // d2*32+l32v

#pragma unroll
        for (int h = 0; h < 2; ++h) {
            __syncthreads();               // K-loop / prev-half reads done
            if ((w >> 1) == h) {
                const int kl0 = wm - h * 64;   // 0 or 32 within the half
#pragma unroll
                for (int i = 0; i < 2; ++i)
#pragma unroll
                    for (int r = 0; r < 4; ++r) {
                        const int kl = kl0 + i * 16 + quad * 4 + r;
#pragma unroll
                        for (int j = 0; j < 4; ++j)
                            L[kl * 68 + j * 16 + l16] = f2bf(acc[i][j][r] + bb[j]);
                    }
            }
            __syncthreads();
            short8 o0, o1;
#pragma unroll
            for (int e = 0; e < 8; ++e) o0[e] = (short)L[(row0 + e) * 68 + dcol];
#pragma unroll
            for (int e = 0; e < 8; ++e) o1[e] = (short)L[(row0 + 8 + e) * 68 + dcol];
            const size_t vb = ((size_t)(bI * NKV + kvv) * 32 + kt0 + h) * 4096
                              + c * 512 + l32v * 16;
            *(short8*)&Vf[vb] = o0;
            *(short8*)&Vf[vb + 8] = o1;
        }
    }
}

// ---------------------------------------------------------------------------
// bf16 MFMA GEMM, 128x64 tile (proj), 3-buffer counted-vmcnt pipeline.
// 1D grid, XCD-swizzled (nx n-blocks, x-fastest).
// C[m][n] = sum_k A[m][k] W[n][k] + b[n]
// ---------------------------------------------------------------------------
template <bool BF16OUT>
__global__ __launch_bounds__(256) void gemm_mfma_kernel(
    const ushort* __restrict__ A, const ushort* __restrict__ W,
    const float* __restrict__ bias, void* __restrict__ Cout,
    int K, int ldc, int nx)
{
    __shared__ ushort SMEM[18432];
    ushort* b0 = SMEM;
    ushort* b1 = SMEM + 6144;
    ushort* b2 = SMEM + 12288;

    const int tid = threadIdx.x;
    const int nwg = gridDim.x;
    const int cpx = nwg >> 3;
    const int bid = blockIdx.x;
    const int swz = (bid & 7) * cpx + (bid >> 3);
    const int bx = swz % nx, by = swz / nx;
    const int m0 = by * 128, n0 = bx * 64;
    const int w = tid >> 6, lane = tid & 63;
    const int quad = lane >> 4, l16 = lane & 15;
    const int wm = w * 32;

    f32x4 acc[2][4] = {};

    float bb[4];
#pragma unroll
    for (int j = 0; j < 4; ++j) bb[j] = bias[n0 + j * 16 + l16];

    const int r0 = tid >> 2;       // 0..63
    const int c8 = (tid & 3) * 8;
    const ushort* Ap = A + (size_t)(m0 + r0) * K + c8;
    const ushort* Wp = W + (size_t)(n0 + r0) * K + c8;

    kloop_pipe3(Ap, Wp, K, b0, b1, b2, w, wm, l16, quad, acc);

#pragma unroll
    for (int i = 0; i < 2; ++i) {
        const int rowb = m0 + wm + i * 16 + quad * 4;
#pragma unroll
        for (int j = 0; j < 4; ++j) {
            const int col = n0 + j * 16 + l16;
#pragma unroll
            for (int r = 0; r < 4; ++r) {
                const float vv = acc[i][j][r] + bb[j];
                if (BF16OUT)
                    ((ushort*)Cout)[(size_t)(rowb + r) * ldc + col] = f2bf(vv);
                else
                    ((float*)Cout)[(size_t)(rowb + r) * ldc + col] = vv;
            }
        }
    }
}

// ---------------------------------------------------------------------------
// Barrier-free S^T-layout MFMA flash attention with in-block k-split.
// Round-0 kernel verbatim (FROZEN).
// ---------------------------------------------------------------------------
__global__ __launch_bounds__(256, 4) void flash_mfma32_kernel(
    const ushort* __restrict__ Qb, const ushort* __restrict__ Kf,
    const ushort* __restrict__ Vf, ushort* __restrict__ Ob)
{
    __shared__ float fsm[4352];            // 2 x (2048 O + 64 m + 64 l) = 17.4KB

    const int qt = blockIdx.x;             // 0..31 (64 q-rows)
    const int bh = blockIdx.y;
    const int b = bh >> 4, h = bh & 15;
    const int kvh = h >> 2;
    const int tid = threadIdx.x;
    const int w = tid >> 6, lane = tid & 63;
    const int l32 = lane & 31, l5 = lane >> 5;
    const int qg = w & 1;                  // q-group within block
    const int kh = w >> 1;                 // k-half

    const ushort* Qg = Qb + ((size_t)bh * N_SEQ + qt * 64 + qg * 32) * HD;
    const size_t kvbase = (size_t)(b * NKV + kvh) * (32 * 4096);
    const ushort* Kp = Kf + kvbase;
    const ushort* Vp = Vf + kvbase;
    const int loff = l32 * 16 + l5 * 8;

    // Q^T B-frags: qF[c][j] = Q[q0+l32][c*16 + l5*8 + j]
    short8 qF[4];
#pragma unroll
    for (int c = 0; c < 4; ++c)
        qF[c] = *(const short8*)&Qg[(size_t)l32 * HD + c * 16 + l5 * 8];

    f32x16 Oa[2] = {};                     // O^T d-tiles (d 0-31, 32-63)
    float mrow = -3.0e38f, lrow = 0.0f;

    for (int i = 0; i < 16; ++i) {
        const int kt = kh * 16 + i;
        const ushort* Kt = Kp + kt * 4096;
        const ushort* Vt = Vp + kt * 4096;

        // direct global->reg fragment loads (coalesced, L2-hit)
        short8 kT[2][4];
#pragma unroll
        for (int s = 0; s < 2; ++s)
#pragma unroll
            for (int c = 0; c < 4; ++c)
                kT[s][c] = *(const short8*)&Kt[(s * 4 + c) * 512 + loff];
        short8 vT[2][2][2];
#pragma unroll
        for (int s = 0; s < 2; ++s)
#pragma unroll
            for (int t = 0; t < 2; ++t)
#pragma unroll
                for (int d2 = 0; d2 < 2; ++d2)
                    vT[s][t][d2] = *(const short8*)&Vt[((s * 2 + t) * 2 + d2) * 512 + loff];

        // S^T (32 keys x 32 q-rows) per key-subtile s
        f32x16 Sv[2] = {};
#pragma unroll
        for (int s = 0; s < 2; ++s)
#pragma unroll
            for (int c = 0; c < 4; ++c)
                Sv[s] = __builtin_amdgcn_mfma_f32_32x32x16_bf16(kT[s][c], qF[c], Sv[s], 0, 0, 0);

        // online softmax (keys in-lane + 1 partner shuffle)
        float mx = -3.0e38f;
#pragma unroll
        for (int s = 0; s < 2; ++s)
#pragma unroll
            for (int r = 0; r < 16; ++r) mx = fmaxf(mx, Sv[s][r]);
        mx = fmaxf(mx, __shfl_xor(mx, 32, 64));
        const float mnew = fmaxf(mrow, mx);
        const float alpha = __expf(mrow - mnew);
        mrow = mnew;
        float rs = 0.0f;
#pragma unroll
        for (int s = 0; s < 2; ++s)
#pragma unroll
            for (int r = 0; r < 16; ++r) {
                Sv[s][r] = __expf(Sv[s][r] - mnew);
                rs += Sv[s][r];
            }
        rs += __shfl_xor(rs, 32, 64);
        lrow = lrow * alpha + rs;
#pragma unroll
        for (int t = 0; t < 2; ++t)
#pragma unroll
            for (int r = 0; r < 16; ++r) Oa[t][r] *= alpha;

        // pack P pairs: P2[s][2g+hh] = keys 8g+4*l5+2hh+{0,1} of subtile s
        uint P2[2][8];
#pragma unroll
        for (int s = 0; s < 2; ++s)
#pragma unroll
            for (int g = 0; g < 4; ++g)
#pragma unroll
                for (int hh = 0; hh < 2; ++hh)
                    P2[s][g * 2 + hh] =
                        pack2bf(Sv[s][4 * g + 2 * hh], Sv[s][4 * g + 2 * hh + 1]);

        // P^T B-frags in-register + PV mfma
#pragma unroll
        for (int s = 0; s < 2; ++s)
#pragma unroll
            for (int t = 0; t < 2; ++t) {
                const uint snd0 = l5 ? P2[s][4 * t + 0] : P2[s][4 * t + 2];
                const uint snd1 = l5 ? P2[s][4 * t + 1] : P2[s][4 * t + 3];
                const uint kp0  = l5 ? P2[s][4 * t + 2] : P2[s][4 * t + 0];
                const uint kp1  = l5 ? P2[s][4 * t + 3] : P2[s][4 * t + 1];
                const uint rcv0 = __shfl_xor(snd0, 32, 64);
                const uint rcv1 = __shfl_xor(snd1, 32, 64);
                union { uint u[4]; short8 s8; } pb;
                pb.u[0] = l5 ? rcv0 : kp0;
                pb.u[1] = l5 ? rcv1 : kp1;
                pb.u[2] = l5 ? kp0 : rcv0;
                pb.u[3] = l5 ? kp1 : rcv1;
#pragma unroll
                for (int d2 = 0; d2 < 2; ++d2)
                    Oa[d2] = __builtin_amdgcn_mfma_f32_32x32x16_bf16(
                        vT[s][t][d2], pb.s8, Oa[d2], 0, 0, 0);
            }
    }

    // ---- merge the two k-halves (wave pairs w, w+2 share q-rows) ----
    float* buf = fsm + qg * 2176;
    if (kh == 1) {
#pragma unroll
        for (int d2 = 0; d2 < 2; ++d2)
#pragma unroll
            for (int r = 0; r < 16; ++r)
                buf[(d2 * 16 + r) * 64 + lane] = Oa[d2][r];
        buf[2048 + lane] = mrow;
        buf[2112 + lane] = lrow;
    }
    __syncthreads();

    if (kh == 0) {
        const float mb = buf[2048 + lane];
        const float lb = buf[2112 + lane];
        const float M = fmaxf(mrow, mb);
        const float ea = __expf(mrow - M), eb = __expf(mb - M);
        lrow = lrow * ea + lb * eb;
#pragma unroll
        for (int d2 = 0; d2 < 2; ++d2)
#pragma unroll
            for (int r = 0; r < 16; ++r)
                Oa[d2][r] = Oa[d2][r] * ea + buf[(d2 * 16 + r) * 64 + lane] * eb;
    }
    __syncthreads();                        // merge reads done before Os reuse

    // ---- epilogue: normalize + transpose to row-major via LDS ----
    ushort* Os = (ushort*)fsm;              // [64][68]
    if (kh == 0) {
        const float inv = 1.0f / lrow;
#pragma unroll
        for (int d2 = 0; d2 < 2; ++d2)
#pragma unroll
            for (int r = 0; r < 16; ++r) {
                const int d = d2 * 32 + (r & 3) + 8 * (r >> 2) + 4 * l5;
                Os[(qg * 32 + l32) * 68 + d] = f2bf(Oa[d2][r] * inv);
            }
    }
    __syncthreads();

    const int row = tid >> 2, cc = (tid & 3) * 16;
#pragma unroll
    for (int i = 0; i < 2; ++i) {
        const short8 v = *(const short8*)&Os[row * 68 + cc + i * 8];
        *(short8*)&Ob[((size_t)b * N_SEQ + qt * 64 + row) * EMB + h * HD + cc + i * 8] = v;
    }
}

// ---------------------------------------------------------------------------
extern "C" void kernel_launch(void* const* d_in, const int* in_sizes, int n_in,
                              void* d_out, int out_size, void* d_ws, size_t ws_size,
                              hipStream_t stream)
{
    const float* x      = (const float*)d_in[0];
    const float* sinp   = (const float*)d_in[1];
    const float* cosp   = (const float*)d_in[2];
    const float* wq_w   = (const float*)d_in[3];
    const float* wq_b   = (const float*)d_in[4];
    const float* wk_w   = (const float*)d_in[5];
    const float* wk_b   = (const float*)d_in[6];
    const float* wv_w   = (const float*)d_in[7];
    const float* wv_b   = (const float*)d_in[8];
    const float* qn_w   = (const float*)d_in[9];
    const float* kn_w   = (const float*)d_in[10];
    const float* proj_w = (const float*)d_in[11];
    const float* proj_b = (const float*)d_in[12];
    float* out = (float*)d_out;

    // workspace layout (ushort elements) — Tq slot retained but unused
    ushort* Tq    = (ushort*)d_ws;            // (unused after r12 fusion)
    ushort* xb    = Tq + 6291456;             // 4096*1024 (reused as Ob)
    ushort* Wqkv  = xb + 4194304;             // 1536*1024
    ushort* Wproj = Wqkv + 1572864;           // 1024*1024
    float*  bqkv  = (float*)(Wproj + 1048576);// 1536
    ushort* Qb    = (ushort*)(bqkv + 1536);   // 2*16*2048*64
    ushort* Kf    = Qb + 4194304;             // frag-order K, 1048576
    ushort* Vf    = Kf + 1048576;             // frag-order V^T, 1048576

    prep_kernel<<<6658, 256, 0, stream>>>(x, wq_w, wk_w, wv_w, proj_w,
                                          wq_b, wk_b, wv_b,
                                          xb, Wqkv, Wproj, bqkv);

    gemm_qkv_fused<<<768, 256, 0, stream>>>(
        xb, Wqkv, bqkv, qn_w, kn_w, sinp, cosp, Qb, Kf, Vf);

    flash_mfma32_kernel<<<dim3(32, 32), 256, 0, stream>>>(Qb, Kf, Vf, xb);

    gemm_mfma_kernel<false><<<512, 256, 0, stream>>>(
        xb, Wproj, proj_b, out, EMB, EMB, 16);
}